// Round 4
// baseline (1092.272 us; speedup 1.0000x reference)
//
#include <hip/hip_runtime.h>
#include <hip/hip_cooperative_groups.h>
#include <math.h>

namespace cg = cooperative_groups;

#define N_INIT 20000
#define LVLS   32
#define PP     1024
#define DD     64
#define DEE    128
#define N_TOT  (N_INIT + LVLS * PP)   // 52768

#define CBLK 256      // coop grid: 1 block/CU guaranteed launchable
#define NPB  4        // nodes per block per level (256*4 = 1024 = PP)
#define ETILE 64      // eval nodes per block

// workspace layout (floats): [0, N_TOT*DD) = store
// at byte offset ACC_OFF: int acc_i[4] = {n_good, n_sel, cnt_pos, cnt_negok}
// at ACC_OFF+16: float acc_f[1] = {loss}
#define STORE_FLOATS (N_TOT * DD)
#define ACC_OFF ((size_t)STORE_FLOATS * 4)

__device__ __forceinline__ float softplusf(float x) {
    return fmaxf(x, 0.f) + log1pf(expf(-fabsf(x)));
}

// ---------------- fused init + 32 levels (cooperative) ----------------
__global__ __launch_bounds__(256, 2) void levels_coop(
    const int* __restrict__ thax, const int* __restrict__ parents,
    const int* __restrict__ rules, const int* __restrict__ sel_mask,
    const int* __restrict__ good_mask, const float* __restrict__ init_table,
    const float* __restrict__ W_rule, const float* __restrict__ b_rule,
    float* __restrict__ store, int* __restrict__ acc_i)
{
    cg::grid_group grid = cg::this_grid();
    const int b = blockIdx.x, t = threadIdx.x;

    __shared__ float pe[NPB][2 * DD];   // 2 KB

    // init store (coalesced float4)
    {
        const float4* tbl4 = (const float4*)init_table;
        float4* st4 = (float4*)store;
        for (int idx = b * 256 + t; idx < N_INIT * 16; idx += CBLK * 256)
            st4[idx] = tbl4[thax[idx >> 4] * 16 + (idx & 15)];
    }
    // mask counts (one shot: 65536 threads >= N_TOT)
    {
        int idx = b * 256 + t;
        bool v = idx < N_TOT;
        bool sel  = v && sel_mask[idx] > 0;
        bool good = sel && good_mask[idx] > 0;
        unsigned long long ms = __ballot(sel), mg = __ballot(good);
        if ((t & 63) == 0) {
            if (mg) atomicAdd(&acc_i[0], (int)__popcll(mg));
            if (ms) atomicAdd(&acc_i[1], (int)__popcll(ms));
        }
    }
    grid.sync();

    for (int l = 0; l < LVLS; ++l) {
        // stage parent vectors: threads 0..127, one float4 each
        if (t < 128) {
            int nb = t >> 5, qq = t & 31;
            int p = b * NPB + nb;
            int pid = parents[(l * PP + p) * 2 + (qq >> 4)];
            ((float4*)pe[nb])[qq] =
                ((const float4*)store)[(size_t)pid * 16 + (qq & 15)];
        }
        __syncthreads();

        // one wave per node: lane = r*16 + q -> cols 4q..4q+3, row slice r
        {
            int wv = t >> 6, lane = t & 63;
            int q = lane & 15, r = lane >> 4;
            int p = b * NPB + wv;
            int ru = rules[l * PP + p];
            const float4* __restrict__ W4 = (const float4*)W_rule + (size_t)ru * 2048;
            const float* pw = pe[wv];
            float4 acc = make_float4(0.f, 0.f, 0.f, 0.f);
#pragma unroll
            for (int i = 0; i < 32; ++i) {
                float4 w = W4[(i * 4 + r) * 16 + q];
                float  s = pw[i * 4 + r];
                acc.x = fmaf(s, w.x, acc.x);
                acc.y = fmaf(s, w.y, acc.y);
                acc.z = fmaf(s, w.z, acc.z);
                acc.w = fmaf(s, w.w, acc.w);
            }
#pragma unroll
            for (int off = 16; off <= 32; off <<= 1) {
                acc.x += __shfl_xor(acc.x, off, 64);
                acc.y += __shfl_xor(acc.y, off, 64);
                acc.z += __shfl_xor(acc.z, off, 64);
                acc.w += __shfl_xor(acc.w, off, 64);
            }
            if (r == 0) {
                float4 bb = ((const float4*)b_rule)[ru * 16 + q];
                float4 h;
                h.x = fmaxf(acc.x + bb.x, 0.f);
                h.y = fmaxf(acc.y + bb.y, 0.f);
                h.z = fmaxf(acc.z + bb.z, 0.f);
                h.w = fmaxf(acc.w + bb.w, 0.f);
                ((float4*)store)[(size_t)(N_INIT + l * PP + p) * 16 + q] = h;
            }
        }
        grid.sync();
    }
}

// ---------------- fallback (proven round-2 kernels) ----------------
__global__ __launch_bounds__(256) void init_kernel(
    float* __restrict__ store, const int* __restrict__ thax,
    const float* __restrict__ init_table,
    const int* __restrict__ sel_mask, const int* __restrict__ good_mask,
    int* __restrict__ acc_i)
{
    int idx = blockIdx.x * 256 + threadIdx.x;
    if (idx < N_INIT * DD) {
        int i = idx >> 6, d = idx & 63;
        store[idx] = init_table[thax[i] * DD + d];
    }
    bool v  = idx < N_TOT;
    bool sel  = v && sel_mask[idx] > 0;
    bool good = sel && (good_mask[idx] > 0);
    unsigned long long ms = __ballot(sel);
    unsigned long long mg = __ballot(good);
    if ((threadIdx.x & 63) == 0) {
        if (mg) atomicAdd(&acc_i[0], (int)__popcll(mg));
        if (ms) atomicAdd(&acc_i[1], (int)__popcll(ms));
    }
}

__global__ __launch_bounds__(256) void level_kernel(
    float* __restrict__ store,
    const int* __restrict__ parents, const int* __restrict__ rules,
    const float* __restrict__ W_rule, const float* __restrict__ b_rule,
    int l)
{
    int p   = blockIdx.x;
    int tid = threadIdx.x;
    int wid  = tid >> 6;
    int lane = tid & 63;
    int q = lane & 15;
    int r = lane >> 4;

    int base = N_INIT + l * PP;
    int pa = parents[(l * PP + p) * 2 + 0];
    int pb = parents[(l * PP + p) * 2 + 1];
    int ru = rules[l * PP + p];

    __shared__ float pe[2 * DD];
    __shared__ float partial[4][DD];

    if (tid < DD)            pe[tid] = store[(size_t)pa * DD + tid];
    else if (tid < 2 * DD)   pe[tid] = store[(size_t)pb * DD + (tid - DD)];
    __syncthreads();

    const float4* __restrict__ W4 = (const float4*)(W_rule + (size_t)ru * (2 * DD * DD));
    float4 acc = make_float4(0.f, 0.f, 0.f, 0.f);
#pragma unroll
    for (int i = 0; i < 8; ++i) {
        int row = wid * 32 + i * 4 + r;
        float4 w = W4[row * 16 + q];
        float  s = pe[row];
        acc.x = fmaf(s, w.x, acc.x);
        acc.y = fmaf(s, w.y, acc.y);
        acc.z = fmaf(s, w.z, acc.z);
        acc.w = fmaf(s, w.w, acc.w);
    }
#pragma unroll
    for (int off = 16; off <= 32; off <<= 1) {
        acc.x += __shfl_xor(acc.x, off, 64);
        acc.y += __shfl_xor(acc.y, off, 64);
        acc.z += __shfl_xor(acc.z, off, 64);
        acc.w += __shfl_xor(acc.w, off, 64);
    }
    if (r == 0) *(float4*)&partial[wid][4 * q] = acc;
    __syncthreads();

    if (tid < DD) {
        float h = partial[0][tid] + partial[1][tid] + partial[2][tid] + partial[3][tid]
                + b_rule[ru * DD + tid];
        store[((size_t)(base + p)) * DD + tid] = fmaxf(h, 0.f);
    }
}

// ---------------- eval: 64 nodes/block, 16 KB LDS, W1 from global ----------------
__global__ __launch_bounds__(256, 4) void eval_kernel(
    const float* __restrict__ store,
    const float* __restrict__ W1, const float* __restrict__ b1,
    const float* __restrict__ w2, const float* __restrict__ b2,
    const int* __restrict__ sel_mask, const int* __restrict__ good_mask,
    int* __restrict__ acc_i, float* __restrict__ acc_f)
{
    __shared__ float sS[ETILE][DD];     // 16 KB
    __shared__ float logitL[ETILE];

    int t = threadIdx.x;
    int base = blockIdx.x * ETILE;

    for (int it = t; it < ETILE * 16; it += 256) {
        int n = it >> 4, qq = it & 15;
        int node = base + n;
        float4 v = make_float4(0.f, 0.f, 0.f, 0.f);
        if (node < N_TOT) v = ((const float4*)store)[(size_t)node * 16 + qq];
        ((float4*)sS[n])[qq] = v;
    }
    __syncthreads();

    int g  = t & 31;      // output col quad
    int n0 = t >> 5;      // node slot base (8 slots)
    const float4* __restrict__ W14 = (const float4*)W1;
    float4 b1v = ((const float4*)b1)[g];
    float4 w2v = ((const float4*)w2)[g];

    float4 a[8];
#pragma unroll
    for (int k = 0; k < 8; ++k) a[k] = b1v;

#pragma unroll
    for (int d4 = 0; d4 < 16; ++d4) {
        float4 w0 = W14[(d4 * 4 + 0) * 32 + g];
        float4 w1 = W14[(d4 * 4 + 1) * 32 + g];
        float4 w2q = W14[(d4 * 4 + 2) * 32 + g];
        float4 w3 = W14[(d4 * 4 + 3) * 32 + g];
#pragma unroll
        for (int k = 0; k < 8; ++k) {
            float4 s = ((const float4*)sS[n0 + 8 * k])[d4];
            a[k].x = fmaf(s.x, w0.x, a[k].x); a[k].y = fmaf(s.x, w0.y, a[k].y);
            a[k].z = fmaf(s.x, w0.z, a[k].z); a[k].w = fmaf(s.x, w0.w, a[k].w);
            a[k].x = fmaf(s.y, w1.x, a[k].x); a[k].y = fmaf(s.y, w1.y, a[k].y);
            a[k].z = fmaf(s.y, w1.z, a[k].z); a[k].w = fmaf(s.y, w1.w, a[k].w);
            a[k].x = fmaf(s.z, w2q.x, a[k].x); a[k].y = fmaf(s.z, w2q.y, a[k].y);
            a[k].z = fmaf(s.z, w2q.z, a[k].z); a[k].w = fmaf(s.z, w2q.w, a[k].w);
            a[k].x = fmaf(s.w, w3.x, a[k].x); a[k].y = fmaf(s.w, w3.y, a[k].y);
            a[k].z = fmaf(s.w, w3.z, a[k].z); a[k].w = fmaf(s.w, w3.w, a[k].w);
        }
    }

    float p[8];
#pragma unroll
    for (int k = 0; k < 8; ++k) {
        p[k] = fmaxf(a[k].x, 0.f) * w2v.x + fmaxf(a[k].y, 0.f) * w2v.y +
               fmaxf(a[k].z, 0.f) * w2v.z + fmaxf(a[k].w, 0.f) * w2v.w;
#pragma unroll
        for (int off = 1; off < 32; off <<= 1)
            p[k] += __shfl_xor(p[k], off, 32);
    }
    if (g == 0) {
        float bb2 = b2[0];
#pragma unroll
        for (int k = 0; k < 8; ++k)
            logitL[n0 + 8 * k] = p[k] + bb2;
    }
    __syncthreads();

    if (t < 64) {
        int node = base + t;
        bool valid = node < N_TOT;
        float logit = logitL[t];
        bool sel  = valid && sel_mask[node] > 0;
        bool good = sel && (good_mask[node] > 0);

        int ng = acc_i[0];
        int ns = acc_i[1];
        int nn = ns - ng;
        float pos_w = ng > 0 ? 0.85f / (float)ng : 1.0f;
        float neg_w = nn > 0 ? 0.15f / (float)nn : 1.0f;

        float bce = softplusf(logit) - logit * (good ? 1.f : 0.f);
        float w   = (good ? pos_w : neg_w) * (sel ? 1.f : 0.f);
        float c   = valid ? w * bce : 0.f;

        int cp = (good && logit >= 0.f) ? 1 : 0;
        int cn = (sel && !good && logit < 0.f) ? 1 : 0;
#pragma unroll
        for (int off = 32; off; off >>= 1) {
            c  += __shfl_down(c, off, 64);
            cp += __shfl_down(cp, off, 64);
            cn += __shfl_down(cn, off, 64);
        }
        if (t == 0) {
            atomicAdd(acc_f, c);
            if (cp) atomicAdd(&acc_i[2], cp);
            if (cn) atomicAdd(&acc_i[3], cn);
        }
    }
}

__global__ void finalize_kernel(float* __restrict__ out,
                                const int* __restrict__ acc_i,
                                const float* __restrict__ acc_f)
{
    int ng = acc_i[0], ns = acc_i[1];
    int nn = ns - ng;
    out[0] = acc_f[0];
    out[1] = ng > 0 ? (float)acc_i[2] / (float)ng : 1.0f;
    out[2] = nn > 0 ? (float)acc_i[3] / (float)nn : 1.0f;
}

extern "C" void kernel_launch(void* const* d_in, const int* in_sizes, int n_in,
                              void* d_out, int out_size, void* d_ws, size_t ws_size,
                              hipStream_t stream) {
    const int*   thax       = (const int*)d_in[0];
    const int*   parents    = (const int*)d_in[1];
    const int*   rules      = (const int*)d_in[2];
    const int*   sel_mask   = (const int*)d_in[3];
    const int*   good_mask  = (const int*)d_in[4];
    const float* init_table = (const float*)d_in[5];
    const float* W_rule     = (const float*)d_in[6];
    const float* b_rule     = (const float*)d_in[7];
    const float* W1         = (const float*)d_in[8];
    const float* b1         = (const float*)d_in[9];
    const float* w2         = (const float*)d_in[10];
    const float* b2         = (const float*)d_in[11];

    float* store = (float*)d_ws;
    int*   acc_i = (int*)((char*)d_ws + ACC_OFF);
    float* acc_f = (float*)((char*)d_ws + ACC_OFF + 16);

    hipMemsetAsync((char*)d_ws + ACC_OFF, 0, 32, stream);

    void* cargs[] = {
        (void*)&thax, (void*)&parents, (void*)&rules, (void*)&sel_mask,
        (void*)&good_mask, (void*)&init_table, (void*)&W_rule, (void*)&b_rule,
        (void*)&store, (void*)&acc_i
    };
    hipError_t cerr = hipLaunchCooperativeKernel((const void*)levels_coop,
                                                 dim3(CBLK), dim3(256),
                                                 cargs, 0, stream);
    if (cerr != hipSuccess) {
        (void)hipGetLastError();   // clear sticky error, use proven fallback
        init_kernel<<<(N_INIT * DD + 255) / 256, 256, 0, stream>>>(
            store, thax, init_table, sel_mask, good_mask, acc_i);
        for (int l = 0; l < LVLS; ++l)
            level_kernel<<<PP, 256, 0, stream>>>(store, parents, rules,
                                                 W_rule, b_rule, l);
    }

    eval_kernel<<<(N_TOT + ETILE - 1) / ETILE, 256, 0, stream>>>(
        store, W1, b1, w2, b2, sel_mask, good_mask, acc_i, acc_f);

    finalize_kernel<<<1, 1, 0, stream>>>((float*)d_out, acc_i, acc_f);
}

// Round 5
// 222.679 us; speedup vs baseline: 4.9051x; 4.9051x over previous
//
#include <hip/hip_runtime.h>
#include <math.h>

#define N_INIT 20000
#define LVLS   32
#define PP     1024
#define DD     64
#define DEE    128
#define N_TOT  (N_INIT + LVLS * PP)   // 52768

#define NBLK 256
#define NTHR 256
#define NPB  4                        // nodes per block per level
#define ETILE 64
#define NTILES ((N_TOT + ETILE - 1) / ETILE)   // 825

// workspace layout:
// [0, N_TOT*DD*4)                      : store (fp32)
// ACC_OFF +0..15  : acc_i[4] = {n_good, n_sel, cnt_pos, cnt_negok}
// ACC_OFF +16     : acc_f (loss)
// ACC_OFF +20     : init_done
// ACC_OFF +24     : eval_done
// FLAG_OFF        : flags[N_TOT]
#define STORE_FLOATS (N_TOT * DD)
#define ACC_OFF  ((size_t)STORE_FLOATS * 4)
#define FLAG_OFF (ACC_OFF + 32)
#define ZERO_BYTES (32 + (size_t)N_TOT * 4)

// device-coherent (sc1) accessors: bypass per-XCD L2, hit coherent MALL
__device__ __forceinline__ float ldf(const float* p) {
    return __hip_atomic_load(p, __ATOMIC_RELAXED, __HIP_MEMORY_SCOPE_AGENT);
}
__device__ __forceinline__ void stf(float* p, float v) {
    __hip_atomic_store(p, v, __ATOMIC_RELAXED, __HIP_MEMORY_SCOPE_AGENT);
}
__device__ __forceinline__ int ldi(const int* p) {
    return __hip_atomic_load(p, __ATOMIC_RELAXED, __HIP_MEMORY_SCOPE_AGENT);
}
__device__ __forceinline__ void sti(int* p, int v) {
    __hip_atomic_store(p, v, __ATOMIC_RELAXED, __HIP_MEMORY_SCOPE_AGENT);
}
__device__ __forceinline__ void wait_vm() {
    asm volatile("s_waitcnt vmcnt(0)" ::: "memory");
}

__device__ __forceinline__ float softplusf(float x) {
    return fmaxf(x, 0.f) + log1pf(expf(-fabsf(x)));
}

__global__ __launch_bounds__(NTHR, 2) void persist_kernel(
    const int* __restrict__ thax, const int* __restrict__ parents,
    const int* __restrict__ rules, const int* __restrict__ sel_mask,
    const int* __restrict__ good_mask, const float* __restrict__ init_table,
    const float* __restrict__ W_rule, const float* __restrict__ b_rule,
    const float* __restrict__ W1, const float* __restrict__ b1,
    const float* __restrict__ w2, const float* __restrict__ b2,
    float* __restrict__ store, int* __restrict__ flags,
    int* __restrict__ acc_i, float* __restrict__ acc_f,
    int* __restrict__ init_done, int* __restrict__ eval_done,
    float* __restrict__ out)
{
    const int b = blockIdx.x, t = threadIdx.x;
    const int lane = t & 63, wv = t >> 6;

    __shared__ float pe[NPB][2 * DD];   // 2 KB
    __shared__ float sS[ETILE][DD];     // 16 KB
    __shared__ float logitL[ETILE];

    // ---------------- init: each wave owns 20 init nodes ----------------
    {
        int wid_g = b * 4 + wv;                  // 0..1023
        int ns = wid_g * 20;
        int ne = ns + 20 > N_INIT ? N_INIT : ns + 20;
        for (int n = ns; n < ne; ++n) {
            float v = init_table[thax[n] * DD + lane];
            stf(&store[(size_t)n * DD + lane], v);
        }
        wait_vm();
        int cnt = ne - ns;
        if (cnt > 0 && lane < cnt) sti(&flags[ns + lane], 1);
    }
    // mask counts (65536 threads >= N_TOT, one shot)
    {
        int idx = b * NTHR + t;
        bool v = idx < N_TOT;
        bool sel  = v && sel_mask[idx] > 0;
        bool good = sel && good_mask[idx] > 0;
        unsigned long long ms = __ballot(sel), mg = __ballot(good);
        if (lane == 0) {
            if (mg) atomicAdd(&acc_i[0], (int)__popcll(mg));
            if (ms) atomicAdd(&acc_i[1], (int)__popcll(ms));
        }
    }
    wait_vm();
    __syncthreads();
    if (t == 0) atomicAdd(init_done, 1);

    // ---------------- 32 DAG levels, flag-gated dataflow ----------------
    for (int l = 0; l < LVLS; ++l) {
        int pbase2 = (l * PP + b * NPB) * 2;     // 8 parent slots
        // wait for this block's 8 parents
        if (t < 2 * NPB) {
            int par = parents[pbase2 + t];
            while (ldi(&flags[par]) == 0) {}
        }
        __syncthreads();                          // also protects pe reuse
        // gather 8 parent rows (512 floats) into LDS, sc1 loads
        {
            int i0 = t, i1 = t + 256;
            int r0 = i0 >> 6, r1 = i1 >> 6;
            int p0 = parents[pbase2 + r0];
            int p1 = parents[pbase2 + r1];
            pe[r0 >> 1][(r0 & 1) * DD + (i0 & 63)] = ldf(&store[(size_t)p0 * DD + (i0 & 63)]);
            pe[r1 >> 1][(r1 & 1) * DD + (i1 & 63)] = ldf(&store[(size_t)p1 * DD + (i1 & 63)]);
        }
        __syncthreads();
        // one wave per node (verified levels_coop math)
        {
            int q = lane & 15, r = lane >> 4;
            int pidx = l * PP + b * NPB + wv;
            int ru = rules[pidx];
            const float4* __restrict__ W4 = (const float4*)W_rule + (size_t)ru * 2048;
            const float* pw = pe[wv];
            float4 acc = make_float4(0.f, 0.f, 0.f, 0.f);
#pragma unroll
            for (int i = 0; i < 32; ++i) {
                float4 w = W4[(i * 4 + r) * 16 + q];
                float  s = pw[i * 4 + r];
                acc.x = fmaf(s, w.x, acc.x);
                acc.y = fmaf(s, w.y, acc.y);
                acc.z = fmaf(s, w.z, acc.z);
                acc.w = fmaf(s, w.w, acc.w);
            }
#pragma unroll
            for (int off = 16; off <= 32; off <<= 1) {
                acc.x += __shfl_xor(acc.x, off, 64);
                acc.y += __shfl_xor(acc.y, off, 64);
                acc.z += __shfl_xor(acc.z, off, 64);
                acc.w += __shfl_xor(acc.w, off, 64);
            }
            int node = N_INIT + pidx;
            if (r == 0) {
                float4 bb = ((const float4*)b_rule)[ru * 16 + q];
                float* dst = &store[(size_t)node * DD + q * 4];
                stf(&dst[0], fmaxf(acc.x + bb.x, 0.f));
                stf(&dst[1], fmaxf(acc.y + bb.y, 0.f));
                stf(&dst[2], fmaxf(acc.z + bb.z, 0.f));
                stf(&dst[3], fmaxf(acc.w + bb.w, 0.f));
            }
            wait_vm();                           // wave-wide: node data at MALL
            if (lane == 0) sti(&flags[node], 1);
        }
    }

    // ---------------- eval + loss (flag-gated tiles) ----------------
    if (t == 0) { while (ldi(init_done) < NBLK) {} }
    __syncthreads();
    int ngood = ldi(&acc_i[0]);
    int nsel  = ldi(&acc_i[1]);
    int nneg  = nsel - ngood;
    float pos_w = ngood > 0 ? 0.85f / (float)ngood : 1.0f;
    float neg_w = nneg  > 0 ? 0.15f / (float)nneg  : 1.0f;

    int g  = t & 31;
    int n0 = t >> 5;
    const float4* __restrict__ W14 = (const float4*)W1;
    float4 b1v = ((const float4*)b1)[g];
    float4 w2v = ((const float4*)w2)[g];
    float  b2v = b2[0];

    float loss_acc = 0.f;
    int   cpos = 0, cneg = 0;

    for (int tile = b; tile < NTILES; tile += NBLK) {
        int base = tile * ETILE;
        int nvalid = N_TOT - base < ETILE ? N_TOT - base : ETILE;
        if (t < nvalid) { while (ldi(&flags[base + t]) == 0) {} }
        __syncthreads();
        for (int it = t; it < nvalid * DD; it += NTHR)
            sS[it >> 6][it & 63] = ldf(&store[(size_t)base * DD + it]);
        if (nvalid < ETILE)
            for (int it = nvalid * DD + t; it < ETILE * DD; it += NTHR)
                sS[it >> 6][it & 63] = 0.f;
        __syncthreads();

        float4 a[8];
#pragma unroll
        for (int k = 0; k < 8; ++k) a[k] = b1v;
#pragma unroll
        for (int d4 = 0; d4 < 16; ++d4) {
            float4 w0 = W14[(d4 * 4 + 0) * 32 + g];
            float4 w1 = W14[(d4 * 4 + 1) * 32 + g];
            float4 w2q = W14[(d4 * 4 + 2) * 32 + g];
            float4 w3 = W14[(d4 * 4 + 3) * 32 + g];
#pragma unroll
            for (int k = 0; k < 8; ++k) {
                float4 s = ((const float4*)sS[n0 + 8 * k])[d4];
                a[k].x = fmaf(s.x, w0.x, a[k].x); a[k].y = fmaf(s.x, w0.y, a[k].y);
                a[k].z = fmaf(s.x, w0.z, a[k].z); a[k].w = fmaf(s.x, w0.w, a[k].w);
                a[k].x = fmaf(s.y, w1.x, a[k].x); a[k].y = fmaf(s.y, w1.y, a[k].y);
                a[k].z = fmaf(s.y, w1.z, a[k].z); a[k].w = fmaf(s.y, w1.w, a[k].w);
                a[k].x = fmaf(s.z, w2q.x, a[k].x); a[k].y = fmaf(s.z, w2q.y, a[k].y);
                a[k].z = fmaf(s.z, w2q.z, a[k].z); a[k].w = fmaf(s.z, w2q.w, a[k].w);
                a[k].x = fmaf(s.w, w3.x, a[k].x); a[k].y = fmaf(s.w, w3.y, a[k].y);
                a[k].z = fmaf(s.w, w3.z, a[k].z); a[k].w = fmaf(s.w, w3.w, a[k].w);
            }
        }
        float p[8];
#pragma unroll
        for (int k = 0; k < 8; ++k) {
            p[k] = fmaxf(a[k].x, 0.f) * w2v.x + fmaxf(a[k].y, 0.f) * w2v.y +
                   fmaxf(a[k].z, 0.f) * w2v.z + fmaxf(a[k].w, 0.f) * w2v.w;
#pragma unroll
            for (int off = 1; off < 32; off <<= 1)
                p[k] += __shfl_xor(p[k], off, 32);
        }
        if (g == 0) {
#pragma unroll
            for (int k = 0; k < 8; ++k)
                logitL[n0 + 8 * k] = p[k] + b2v;
        }
        __syncthreads();

        if (t < 64) {
            int node = base + t;
            bool valid = t < nvalid;
            float logit = logitL[t];
            bool sel  = valid && sel_mask[node] > 0;
            bool good = sel && (good_mask[node] > 0);
            float bce = softplusf(logit) - logit * (good ? 1.f : 0.f);
            float w   = (good ? pos_w : neg_w) * (sel ? 1.f : 0.f);
            loss_acc += valid ? w * bce : 0.f;
            cpos += (good && logit >= 0.f) ? 1 : 0;
            cneg += (sel && !good && logit < 0.f) ? 1 : 0;
        }
        __syncthreads();
    }

    if (t < 64) {
        float c = loss_acc;
        int cp = cpos, cn = cneg;
#pragma unroll
        for (int off = 32; off; off >>= 1) {
            c  += __shfl_down(c, off, 64);
            cp += __shfl_down(cp, off, 64);
            cn += __shfl_down(cn, off, 64);
        }
        if (t == 0) {
            atomicAdd(acc_f, c);
            if (cp) atomicAdd(&acc_i[2], cp);
            if (cn) atomicAdd(&acc_i[3], cn);
            wait_vm();                                 // partials at MALL
            int old = atomicAdd(eval_done, 1);
            if (old == NBLK - 1) {                     // last block finalizes
                int ng = ldi(&acc_i[0]);
                int ns = ldi(&acc_i[1]);
                int cp2 = ldi(&acc_i[2]);
                int cn2 = ldi(&acc_i[3]);
                float lf = ldf(acc_f);
                int nn = ns - ng;
                stf(&out[0], lf);
                stf(&out[1], ng > 0 ? (float)cp2 / (float)ng : 1.0f);
                stf(&out[2], nn > 0 ? (float)cn2 / (float)nn : 1.0f);
            }
        }
    }
}

extern "C" void kernel_launch(void* const* d_in, const int* in_sizes, int n_in,
                              void* d_out, int out_size, void* d_ws, size_t ws_size,
                              hipStream_t stream) {
    const int*   thax       = (const int*)d_in[0];
    const int*   parents    = (const int*)d_in[1];
    const int*   rules      = (const int*)d_in[2];
    const int*   sel_mask   = (const int*)d_in[3];
    const int*   good_mask  = (const int*)d_in[4];
    const float* init_table = (const float*)d_in[5];
    const float* W_rule     = (const float*)d_in[6];
    const float* b_rule     = (const float*)d_in[7];
    const float* W1         = (const float*)d_in[8];
    const float* b1         = (const float*)d_in[9];
    const float* w2         = (const float*)d_in[10];
    const float* b2         = (const float*)d_in[11];

    float* store     = (float*)d_ws;
    int*   acc_i     = (int*)((char*)d_ws + ACC_OFF);
    float* acc_f     = (float*)((char*)d_ws + ACC_OFF + 16);
    int*   init_done = (int*)((char*)d_ws + ACC_OFF + 20);
    int*   eval_done = (int*)((char*)d_ws + ACC_OFF + 24);
    int*   flags     = (int*)((char*)d_ws + FLAG_OFF);

    // zero accumulators + flags (graph-capture-safe)
    hipMemsetAsync((char*)d_ws + ACC_OFF, 0, ZERO_BYTES, stream);

    persist_kernel<<<NBLK, NTHR, 0, stream>>>(
        thax, parents, rules, sel_mask, good_mask, init_table,
        W_rule, b_rule, W1, b1, w2, b2,
        store, flags, acc_i, acc_f, init_done, eval_done, (float*)d_out);
}